// Round 15
// baseline (62.203 us; speedup 1.0000x reference)
//
#include <hip/hip_runtime.h>
#include <hip/hip_bf16.h>
#include <math.h>

#define COUPLING 0.12f
#define EPSV 1e-8f
#define SCALE2L2E 2.8853900817779268f   // 2*log2(e): folds tanh's 2x and exp->exp2

typedef __attribute__((ext_vector_type(8))) short bf16x8;
typedef __attribute__((ext_vector_type(4))) float f32x4;

// tanh(x) from y = 2x*log2(e):  tanh = 1 - 2/(1+2^y). Inf-safe both ways.
__device__ __forceinline__ float tanh_from_e2(float y) {
    float e = __builtin_amdgcn_exp2f(y);
    float r = __builtin_amdgcn_rcpf(1.0f + e);
    return fmaf(-2.0f, r, 1.0f);
}
__device__ __forceinline__ float tanh_fast(float x) {
    return tanh_from_e2(SCALE2L2E * x);
}
// sigma(y) = 1/(1+2^y); tanh = 1 - 2*sigma.
__device__ __forceinline__ float sig_e2(float y) {
    float e = __builtin_amdgcn_exp2f(y);
    return __builtin_amdgcn_rcpf(1.0f + e);
}

__device__ __forceinline__ short f2bf(float f) {
    __hip_bfloat16 h = __float2bfloat16(f);
    return __builtin_bit_cast(short, h);
}

// Main, round-18. R14's smoking gun: VGPR=28 -- the depth-2 prefetch's
// live set (>=40) cannot fit in 28 regs, so the compiler SANK the loads to
// just-before-use, deleting the software pipeline. Result: full memory
// latency exposed serially 16x, all waves phase-locked (42.5us, VALUBusy
// 29%, Occupancy 70% -- residency worked, prefetch didn't). Everything
// else was right: no barriers, no spill (WRITE 1MB), FETCH 33MB (z_past
// half-L3-resident across bench iters -- supply is cheap, only latency
// hiding missing). Fix: PIN a depth-4 register pipeline.
//  - 4 NAMED pre-sets (rule #20), loop unrolled x4 (uni requires K%4==0;
//    bench K=16).
//  - Per sub-step: [cvt set j -> a] [reload set j <- tile k+4, clamped
//    unconditional address] [sched_barrier(0)] [MFMA+sigmas]. The barrier
//    forbids sinking loads below the math; data is 3 compute bodies old at
//    consumption -> counted vmcnt, ~2000cy of cover.
// C/D layout: col=lane&15, row=(lane>>4)*4+reg (m89-verified).
__global__ __launch_bounds__(256, 4) void phot_main(
    const float* __restrict__ z_past,   // [P][32] fp32
    const float* __restrict__ heads_w,  // [128][64]
    const float* __restrict__ heads_b,  // [128]
    const float* __restrict__ cand,     // [32]
    float* __restrict__ partials,       // [NB][128]
    int P, int NB)                      // NB = grid size
{
    __shared__ float wacc[128];
    __shared__ float cpre_l[128];

    const int tid  = threadIdx.x;
    const int lane = tid & 63;
    const int wv   = tid >> 6;
    const int col  = lane & 15;   // A-row / B-col / C-col
    const int kg   = lane >> 4;   // k-group (k = kg*8 + e)

    // ---- prep: cpre into LDS (one barrier, outside the loop) ----
    if (tid < 128) {
        const float* wr = heads_w + (size_t)tid * 64;
        float s0 = heads_b[tid], s1 = 0.f, s2 = 0.f, s3 = 0.f;
        #pragma unroll
        for (int k = 0; k < 32; k += 4) {
            s0 = fmaf(wr[k+0], cand[k+0], s0);
            s1 = fmaf(wr[k+1], cand[k+1], s1);
            s2 = fmaf(wr[k+2], cand[k+2], s2);
            s3 = fmaf(wr[k+3], cand[k+3], s3);
        }
        cpre_l[tid] = SCALE2L2E * ((s0 + s1) + (s2 + s3));
    }

    // This wave's 2 channel groups: B-fragments built in registers from
    // L2-resident heads_w (single-use -> no LDS needed).
    const int g0i = wv * 2, g1i = g0i + 1;
    bf16x8 bfA, bfB;
    {
        const float* wA = heads_w + (size_t)(g0i * 16 + col) * 64 + 32 + kg * 8;
        const float* wB = heads_w + (size_t)(g1i * 16 + col) * 64 + 32 + kg * 8;
        f32x4 a0 = *(const f32x4*)wA, a1 = *(const f32x4*)(wA + 4);
        f32x4 b0 = *(const f32x4*)wB, b1 = *(const f32x4*)(wB + 4);
        bfA[0]=f2bf(SCALE2L2E*a0[0]); bfA[1]=f2bf(SCALE2L2E*a0[1]);
        bfA[2]=f2bf(SCALE2L2E*a0[2]); bfA[3]=f2bf(SCALE2L2E*a0[3]);
        bfA[4]=f2bf(SCALE2L2E*a1[0]); bfA[5]=f2bf(SCALE2L2E*a1[1]);
        bfA[6]=f2bf(SCALE2L2E*a1[2]); bfA[7]=f2bf(SCALE2L2E*a1[3]);
        bfB[0]=f2bf(SCALE2L2E*b0[0]); bfB[1]=f2bf(SCALE2L2E*b0[1]);
        bfB[2]=f2bf(SCALE2L2E*b0[2]); bfB[3]=f2bf(SCALE2L2E*b0[3]);
        bfB[4]=f2bf(SCALE2L2E*b1[0]); bfB[5]=f2bf(SCALE2L2E*b1[1]);
        bfB[6]=f2bf(SCALE2L2E*b1[2]); bfB[7]=f2bf(SCALE2L2E*b1[3]);
    }
    __syncthreads();
    const float cpA = cpre_l[g0i * 16 + col];
    const float cpB = cpre_l[g1i * 16 + col];
    const f32x4 cvA = {cpA, cpA, cpA, cpA};
    const f32x4 cvB = {cpB, cpB, cpB, cpB};

    f32x4 accA = {0,0,0,0}, accB = {0,0,0,0};

    const int T  = (P + 15) >> 4;             // total 16-row tiles
    const int Tf = P >> 4;                    // full tiles
    const int b  = blockIdx.x;
    const int K  = (b < T) ? ((T - 1 - b) / NB + 1) : 0;   // tiles for this block

    // Uniform fast path: no partial tile, equal K, K%4==0 (bench: K=16).
    const bool uni = ((T % NB) == 0) && (Tf == T) && ((K & 3) == 0);

    if (K > 0) {
        if (uni) {
            // Depth-4 pinned register pipeline.
            const float* gb = z_past + ((size_t)(b * 16 + col)) * 32 + kg * 8;
            const size_t step = (size_t)NB * 512;   // floats between tiles

            f32x4 pl0, ph0, pl1, ph1, pl2, ph2, pl3, ph3;

            #define LOADSET(S, kt) { \
                int tn_ = (kt); if (tn_ > K - 1) tn_ = K - 1; \
                const float* gp_ = gb + (size_t)tn_ * step; \
                pl##S = *(const f32x4*)gp_; \
                ph##S = *(const f32x4*)(gp_ + 4); }
            #define SUBSTEP(S, knext) { \
                bf16x8 a_; \
                a_[0]=f2bf(pl##S[0]); a_[1]=f2bf(pl##S[1]); \
                a_[2]=f2bf(pl##S[2]); a_[3]=f2bf(pl##S[3]); \
                a_[4]=f2bf(ph##S[0]); a_[5]=f2bf(ph##S[1]); \
                a_[6]=f2bf(ph##S[2]); a_[7]=f2bf(ph##S[3]); \
                LOADSET(S, knext) \
                __builtin_amdgcn_sched_barrier(0); \
                f32x4 d_ = __builtin_amdgcn_mfma_f32_16x16x32_bf16(a_, bfA, cvA, 0, 0, 0); \
                accA[0] += sig_e2(d_[0]); accA[1] += sig_e2(d_[1]); \
                accA[2] += sig_e2(d_[2]); accA[3] += sig_e2(d_[3]); \
                d_ = __builtin_amdgcn_mfma_f32_16x16x32_bf16(a_, bfB, cvB, 0, 0, 0); \
                accB[0] += sig_e2(d_[0]); accB[1] += sig_e2(d_[1]); \
                accB[2] += sig_e2(d_[2]); accB[3] += sig_e2(d_[3]); }

            LOADSET(0, 0) LOADSET(1, 1) LOADSET(2, 2) LOADSET(3, 3)
            for (int kb = 0; kb < K; kb += 4) {
                SUBSTEP(0, kb + 4)
                SUBSTEP(1, kb + 5)
                SUBSTEP(2, kb + 6)
                SUBSTEP(3, kb + 7)
            }
            #undef LOADSET
            #undef SUBSTEP
        } else {
            // General path: clamped loads + per-element guards (R0-proven).
            for (int k = 0; k < K; ++k) {
                const int t = b + k * NB;
                int row = t * 16 + col; if (row > P - 1) row = P - 1;
                const float* g = z_past + (size_t)row * 32 + kg * 8;
                f32x4 cl = *(const f32x4*)g;
                f32x4 ch = *(const f32x4*)(g + 4);
                bf16x8 a;
                a[0]=f2bf(cl[0]); a[1]=f2bf(cl[1]); a[2]=f2bf(cl[2]); a[3]=f2bf(cl[3]);
                a[4]=f2bf(ch[0]); a[5]=f2bf(ch[1]); a[6]=f2bf(ch[2]); a[7]=f2bf(ch[3]);
                const int base = t * 16;
                if (base + 16 <= P) {
                    f32x4 d = __builtin_amdgcn_mfma_f32_16x16x32_bf16(a, bfA, cvA, 0, 0, 0);
                    accA[0] += sig_e2(d[0]); accA[1] += sig_e2(d[1]);
                    accA[2] += sig_e2(d[2]); accA[3] += sig_e2(d[3]);
                    d = __builtin_amdgcn_mfma_f32_16x16x32_bf16(a, bfB, cvB, 0, 0, 0);
                    accB[0] += sig_e2(d[0]); accB[1] += sig_e2(d[1]);
                    accB[2] += sig_e2(d[2]); accB[3] += sig_e2(d[3]);
                } else {
                    const int r0 = base + kg * 4;
                    f32x4 d = __builtin_amdgcn_mfma_f32_16x16x32_bf16(a, bfA, cvA, 0, 0, 0);
                    if (r0 + 0 < P) accA[0] += sig_e2(d[0]);
                    if (r0 + 1 < P) accA[1] += sig_e2(d[1]);
                    if (r0 + 2 < P) accA[2] += sig_e2(d[2]);
                    if (r0 + 3 < P) accA[3] += sig_e2(d[3]);
                    d = __builtin_amdgcn_mfma_f32_16x16x32_bf16(a, bfB, cvB, 0, 0, 0);
                    if (r0 + 0 < P) accB[0] += sig_e2(d[0]);
                    if (r0 + 1 < P) accB[1] += sig_e2(d[1]);
                    if (r0 + 2 < P) accB[2] += sig_e2(d[2]);
                    if (r0 + 3 < P) accB[3] += sig_e2(d[3]);
                }
            }
        }
    }

    // Per-lane valid-row count (analytic).
    float nsum = 0.0f;
    if (K > 0) {
        int nfull = (b < Tf) ? ((Tf - 1 - b) / NB + 1) : 0;
        nsum = 4.0f * (float)nfull;
        if (Tf < T && b <= Tf && ((Tf - b) % NB) == 0) {   // block owns partial tile
            int prem = P - Tf * 16;
            int nv = prem - kg * 4; if (nv < 0) nv = 0; if (nv > 4) nv = 4;
            nsum += (float)nv;
        }
    }

    // sum(tanh) = nsum - 2*sum(sigma); fold 4 row-regs, then 4 k-groups.
    float sA = nsum - 2.0f * ((accA[0] + accA[1]) + (accA[2] + accA[3]));
    sA += __shfl_xor(sA, 16, 64);
    sA += __shfl_xor(sA, 32, 64);
    float sB = nsum - 2.0f * ((accB[0] + accB[1]) + (accB[2] + accB[3]));
    sB += __shfl_xor(sB, 16, 64);
    sB += __shfl_xor(sB, 32, 64);
    if (lane < 16) {
        wacc[g0i * 16 + lane] = sA;
        wacc[g1i * 16 + lane] = sB;
    }
    __syncthreads();
    if (tid < 128) {
        partials[(size_t)b * 128 + tid] = wacc[tid];
    }
}

// Finalize: generic 16-deep-ILP partials reduction (256B/lane in flight;
// the cross-XCD read is latency-bound). cnt = nblk/32 = 64 at nblk=2048.
__global__ __launch_bounds__(1024) void phot_finalize(
    const float* __restrict__ partials, int nblk, int P,
    const float* __restrict__ out_w,      // [32][128]
    const float* __restrict__ out_b,      // [32]
    const float* __restrict__ rel_bias,   // [129][2]
    const float* __restrict__ cand,       // [32]
    const float* __restrict__ norm_scale, // [1]
    const int* __restrict__ posp,         // [1]
    float* __restrict__ out)              // [32]
{
    __shared__ __align__(16) float sh[4096];   // [slice 0..31][128 ch]
    __shared__ float  cm[128];
    __shared__ float  outv[32];
    __shared__ double db[512];
    __shared__ float  bm[2];

    const int t   = threadIdx.x;
    const int chg = t & 31;         // channel group (4 channels)
    const int sl  = t >> 5;         // 0..31 slices over blocks

    const int cnt = nblk >> 5;      // nblk is a multiple of 32
    const float* p0 = partials + (size_t)(sl * cnt) * 128 + chg * 4;
    f32x4 s0 = {0,0,0,0}, s1 = {0,0,0,0}, s2 = {0,0,0,0}, s3 = {0,0,0,0};
    int i = 0;
    for (; i + 16 <= cnt; i += 16) {
        f32x4 v[16];
        #pragma unroll
        for (int j = 0; j < 16; ++j)
            v[j] = *(const f32x4*)(p0 + (size_t)(i + j) * 128);
        #pragma unroll
        for (int j = 0; j < 16; j += 4) {
            s0 += v[j+0]; s1 += v[j+1]; s2 += v[j+2]; s3 += v[j+3];
        }
    }
    for (; i < cnt; ++i) s0 += *(const f32x4*)(p0 + (size_t)i * 128);
    f32x4 acc = (s0 + s1) + (s2 + s3);
    *(f32x4*)&sh[sl * 128 + chg * 4] = acc;
    __syncthreads();

    if (t < 128) {
        float s = 0.0f;
        #pragma unroll
        for (int s2i = 0; s2i < 32; ++s2i) s += sh[t + 128 * s2i];
        cm[t] = s / (float)P;
    }

    // rel-bias mean, closed form per bin; idx(p)=clamp(a+p,0,128), a=pos-P+64
    if (t < 512) {
        const int c = t >> 8, j = t & 255;
        double v = 0.0;
        if (j <= 128) {
            const long long pos = (long long)(*posp);
            const long long a = pos - (long long)P + 64;
            double cnt2;
            if (j == 0) {
                long long hi = -a; if (hi > (long long)P - 1) hi = (long long)P - 1;
                cnt2 = (hi >= 0) ? (double)(hi + 1) : 0.0;
            } else if (j == 128) {
                long long lo = 128 - a; if (lo < 0) lo = 0;
                cnt2 = (lo <= (long long)P - 1) ? (double)((long long)P - lo) : 0.0;
            } else {
                long long p = (long long)j - a;
                cnt2 = (p >= 0 && p < (long long)P) ? 1.0 : 0.0;
            }
            v = cnt2 * (double)rel_bias[2*j + c];
        }
        db[t] = v;
    }
    __syncthreads();
    #pragma unroll
    for (int s = 128; s >= 1; s >>= 1) {
        if (t < 512 && (t & 255) < s) db[t] += db[t + s];
        __syncthreads();
    }
    if (t < 2) bm[t] = (float)(db[t << 8] / (double)P);
    __syncthreads();

    if (t < 32) {
        const float* wr = out_w + t * 128;
        float o0 = out_b[t], o1 = 0.f, o2 = 0.f, o3 = 0.f;
        #pragma unroll
        for (int j = 0; j < 128; j += 4) {
            o0 = fmaf(wr[j+0], cm[j+0], o0);
            o1 = fmaf(wr[j+1], cm[j+1], o1);
            o2 = fmaf(wr[j+2], cm[j+2], o2);
            o3 = fmaf(wr[j+3], cm[j+3], o3);
        }
        outv[t] = (o0+o1) + (o2+o3);
    }
    __syncthreads();

    if (t < 32) {
        float zt = tanh_fast(cand[t] + COUPLING * (outv[t] + bm[t & 1]));
        float other = __shfl_xor(zt, 1, 64);
        float m = fmaf(zt, zt, other * other);
        #pragma unroll
        for (int off = 2; off < 32; off <<= 1) m = fmaxf(m, __shfl_xor(m, off, 64));
        float scale = norm_scale[0] / sqrtf(m + EPSV);
        out[t] = (m > 0.0f) ? zt * scale : zt;
    }
}

extern "C" void kernel_launch(void* const* d_in, const int* in_sizes, int n_in,
                              void* d_out, int out_size, void* d_ws, size_t ws_size,
                              hipStream_t stream)
{
    const float* cand       = (const float*)d_in[0];
    const float* z_past     = (const float*)d_in[1];
    const float* heads_w    = (const float*)d_in[2];
    const float* heads_b    = (const float*)d_in[3];
    const float* out_w      = (const float*)d_in[4];
    const float* out_b      = (const float*)d_in[5];
    const float* rel_bias   = (const float*)d_in[6];
    const float* norm_scale = (const float*)d_in[7];
    const int*   posp       = (const int*)d_in[8];

    const int P = in_sizes[1] / 32;

    int nblk = 2048;     // 8 blocks/CU by actual usage: ~56-64 VGPR, ~1KB LDS
    size_t need = (size_t)nblk * 128 * sizeof(float);
    if (need > ws_size) {
        nblk = (int)(ws_size / (128 * sizeof(float)));
        nblk &= ~31;
        if (nblk < 32) nblk = 32;
    }
    float* partials = (float*)d_ws;

    phot_main<<<nblk, 256, 0, stream>>>(z_past, heads_w, heads_b, cand,
                                        partials, P, nblk);
    phot_finalize<<<1, 1024, 0, stream>>>(partials, nblk, P, out_w, out_b,
                                          rel_bias, cand, norm_scale, posp,
                                          (float*)d_out);
}

// Round 16
// 43.461 us; speedup vs baseline: 1.4312x; 1.4312x over previous
//
#include <hip/hip_runtime.h>
#include <hip/hip_bf16.h>
#include <math.h>

#define COUPLING 0.12f
#define EPSV 1e-8f
#define SCALE2L2E 2.8853900817779268f   // 2*log2(e): folds tanh's 2x and exp->exp2

typedef __attribute__((ext_vector_type(8))) short bf16x8;
typedef __attribute__((ext_vector_type(4))) float f32x4;

// tanh(x) from y = 2x*log2(e):  tanh = 1 - 2/(1+2^y). Inf-safe both ways.
__device__ __forceinline__ float tanh_from_e2(float y) {
    float e = __builtin_amdgcn_exp2f(y);
    float r = __builtin_amdgcn_rcpf(1.0f + e);
    return fmaf(-2.0f, r, 1.0f);
}
__device__ __forceinline__ float tanh_fast(float x) {
    return tanh_from_e2(SCALE2L2E * x);
}
// sigma(y) = 1/(1+2^y); tanh = 1 - 2*sigma.
__device__ __forceinline__ float sig_e2(float y) {
    float e = __builtin_amdgcn_exp2f(y);
    return __builtin_amdgcn_rcpf(1.0f + e);
}

__device__ __forceinline__ short f2bf(float f) {
    __hip_bfloat16 h = __float2bfloat16(f);
    return __builtin_bit_cast(short, h);
}

// Main, round-19: REVERT to the R11-benched best (35.78us; LDS pipeline,
// wbf_l, 2-way swizzle, uniform fast path) + the ONE clean occupancy lever:
//  - zb ring-3 -> ring-2. Safety proof for this schedule: phase p's
//    ds_reads of slot p&1 complete before phase p's lgkmcnt(0)+s_barrier;
//    the overwrite of slot p&1 happens at the BOTTOM of phase p+1, i.e.
//    after that barrier. (R8's ring-2 failure was confounded by the 4-way
//    swizzle + LDS-granule straggler, both since fixed.)
//  - LDS 21.3 -> 17.3KB: 8 x 17.3 = 139KB <= 160KB -> 8 blocks/CU fits
//    even with multi-KB allocation granularity. nblk=2048 keeps T%NB==0
//    (uniform path, K=16, PH=4 even). VGPR stays the measured-44 body;
//    launch_bounds stays (256,4) -- no allocator clamp (R12's lesson).
// The no-LDS line (R13-R15) is abandoned: 4 rounds, 4 regressions
// (compiler sank prefetches at VGPR=28; sched_barrier(0) fences serialized
// the body at VGPR=48).
// C/D layout: col=lane&15, row=(lane>>4)*4+reg (m89-verified).
__global__ __launch_bounds__(256, 4) void phot_main(
    const float* __restrict__ z_past,   // [P][32] fp32
    const float* __restrict__ heads_w,  // [128][64]
    const float* __restrict__ heads_b,  // [128]
    const float* __restrict__ cand,     // [32]
    float* __restrict__ partials,       // [NB][128]
    int P, int NB)                      // NB = grid size
{
    __shared__ float wacc[128];
    __shared__ float cpre_l[128];
    __shared__ __align__(16) unsigned short wbf_l[128][32];   // 8KB bf16 weights
    __shared__ __align__(16) unsigned short zb[2][4][512];    // ring-2: [slot][tile][16x32]

    const int tid  = threadIdx.x;
    const int lane = tid & 63;
    const int wv   = tid >> 6;
    const int col  = lane & 15;   // A-row / B-col / C-col
    const int kg   = lane >> 4;   // k-group (k = kg*8 + e)

    // ---- prep phase (block-local) ----
    if (tid < 128) {
        const float* wr = heads_w + (size_t)tid * 64;
        float s0 = heads_b[tid], s1 = 0.f, s2 = 0.f, s3 = 0.f;
        #pragma unroll
        for (int k = 0; k < 32; k += 4) {
            s0 = fmaf(wr[k+0], cand[k+0], s0);
            s1 = fmaf(wr[k+1], cand[k+1], s1);
            s2 = fmaf(wr[k+2], cand[k+2], s2);
            s3 = fmaf(wr[k+3], cand[k+3], s3);
        }
        cpre_l[tid] = SCALE2L2E * ((s0 + s1) + (s2 + s3));
        #pragma unroll
        for (int k = 0; k < 32; ++k)
            wbf_l[tid][k] = (unsigned short)f2bf(SCALE2L2E * wr[32 + k]);
    }
    __syncthreads();

    // This wave's 2 channel groups (B fragments from LDS).
    const int g0 = wv * 2, g1 = g0 + 1;
    const bf16x8 bfA = *(const bf16x8*)&wbf_l[g0 * 16 + col][kg * 8];
    const bf16x8 bfB = *(const bf16x8*)&wbf_l[g1 * 16 + col][kg * 8];
    const float  cpA = cpre_l[g0 * 16 + col];
    const float  cpB = cpre_l[g1 * 16 + col];
    const f32x4  cvA = {cpA, cpA, cpA, cpA};   // hoisted MFMA C operands
    const f32x4  cvB = {cpB, cpB, cpB, cpB};

    f32x4 accA = {0,0,0,0}, accB = {0,0,0,0};

    const int T  = (P + 15) >> 4;             // total 16-row tiles
    const int Tf = P >> 4;                    // full tiles
    const int b  = blockIdx.x;
    const int K  = (b < T) ? ((T - 1 - b) / NB + 1) : 0;   // tiles for this block
    const int PH = (K + 3) >> 2;              // phases of 4 tiles

    // Uniform shape: every block has the same K, no partial tile, PH even.
    const bool uni = ((T % NB) == 0) && (Tf == T) && ((K & 7) == 0);

    // Stager lane mapping: lane covers tile floats [sr*32 + sc*8, +8).
    const int sr = lane >> 2;                 // row 0..15
    const int sc = lane & 3;                  // chunk 0..3 (8 floats = 16B bf16)
    // Verified 2-way swizzle: slot = chunk ^ ((row>>1)&3).
    const int woff = sr * 32 + ((sc ^ ((sr >> 1) & 3)) << 3);   // ushort offset
    const int roff = col * 32 + ((kg ^ ((col >> 1) & 3)) << 3); // ushort offset

    // Two named prefetch register sets; phase q's data lives in set (q&1).
    f32x4 preA0, preB0, preA1, preB1;

    #define SLOADP(ph, S) { \
        const int j_ = 4 * (ph) + wv; \
        if (j_ < K) { \
            const int tt_ = b + j_ * NB; \
            int grow = tt_ * 16 + sr; if (grow > P - 1) grow = P - 1; \
            const float* g_ = z_past + (size_t)grow * 32 + sc * 8; \
            preA##S = *(const f32x4*)g_; \
            preB##S = *(const f32x4*)(g_ + 4); \
        } }
    #define SWRITEP(ph, S) { \
        const int j_ = 4 * (ph) + wv; \
        if (j_ < K) { \
            bf16x8 w_; \
            w_[0]=f2bf(preA##S[0]); w_[1]=f2bf(preA##S[1]); \
            w_[2]=f2bf(preA##S[2]); w_[3]=f2bf(preA##S[3]); \
            w_[4]=f2bf(preB##S[0]); w_[5]=f2bf(preB##S[1]); \
            w_[6]=f2bf(preB##S[2]); w_[7]=f2bf(preB##S[3]); \
            *(bf16x8*)(&zb[(ph) & 1][wv][woff]) = w_; \
        } }
    // Fast-path tile: no guards, no tail (uniform shape only).
    #define CTILE_F(p, j) { \
        const bf16x8 a_ = *(const bf16x8*)(&zb[(p) & 1][j][roff]); \
        f32x4 d_ = __builtin_amdgcn_mfma_f32_16x16x32_bf16(a_, bfA, cvA, 0, 0, 0); \
        accA[0] += sig_e2(d_[0]); accA[1] += sig_e2(d_[1]); \
        accA[2] += sig_e2(d_[2]); accA[3] += sig_e2(d_[3]); \
        d_ = __builtin_amdgcn_mfma_f32_16x16x32_bf16(a_, bfB, cvB, 0, 0, 0); \
        accB[0] += sig_e2(d_[0]); accB[1] += sig_e2(d_[1]); \
        accB[2] += sig_e2(d_[2]); accB[3] += sig_e2(d_[3]); }
    // Guarded tile (general shapes).
    #define CTILE_G(p, j) { \
        const int jj_ = 4 * (p) + (j); \
        if (jj_ < K) { \
            const int tt_ = b + jj_ * NB; \
            const bf16x8 a_ = *(const bf16x8*)(&zb[(p) & 1][j][roff]); \
            const int base_ = tt_ * 16; \
            if (base_ + 16 <= P) { \
                f32x4 d_ = __builtin_amdgcn_mfma_f32_16x16x32_bf16(a_, bfA, cvA, 0, 0, 0); \
                accA[0] += sig_e2(d_[0]); accA[1] += sig_e2(d_[1]); \
                accA[2] += sig_e2(d_[2]); accA[3] += sig_e2(d_[3]); \
                d_ = __builtin_amdgcn_mfma_f32_16x16x32_bf16(a_, bfB, cvB, 0, 0, 0); \
                accB[0] += sig_e2(d_[0]); accB[1] += sig_e2(d_[1]); \
                accB[2] += sig_e2(d_[2]); accB[3] += sig_e2(d_[3]); \
            } else { \
                const int r0_ = base_ + kg * 4; \
                f32x4 d_ = __builtin_amdgcn_mfma_f32_16x16x32_bf16(a_, bfA, cvA, 0, 0, 0); \
                if (r0_ + 0 < P) accA[0] += sig_e2(d_[0]); \
                if (r0_ + 1 < P) accA[1] += sig_e2(d_[1]); \
                if (r0_ + 2 < P) accA[2] += sig_e2(d_[2]); \
                if (r0_ + 3 < P) accA[3] += sig_e2(d_[3]); \
                d_ = __builtin_amdgcn_mfma_f32_16x16x32_bf16(a_, bfB, cvB, 0, 0, 0); \
                if (r0_ + 0 < P) accB[0] += sig_e2(d_[0]); \
                if (r0_ + 1 < P) accB[1] += sig_e2(d_[1]); \
                if (r0_ + 2 < P) accB[2] += sig_e2(d_[2]); \
                if (r0_ + 3 < P) accB[3] += sig_e2(d_[3]); \
            } \
        } }

    #define SYNC { asm volatile("s_waitcnt lgkmcnt(0)" ::: "memory"); \
                   __builtin_amdgcn_s_barrier(); \
                   __builtin_amdgcn_sched_barrier(0); }

    if (K > 0) {
        // Prologue: phase-0 data -> set 0, publish; phase-1 data -> set 1.
        SLOADP(0, 0)
        SWRITEP(0, 0)             // vmcnt wait (prologue, once)
        SLOADP(1, 1)
        SYNC

        if (uni) {
            // Hot path: loads at phase TOP, publish at BOTTOM, no tile guards.
            for (int p = 0; p < PH; p += 2) {
                {
                    SLOADP(p + 2, 0)
                    CTILE_F(p, 0) CTILE_F(p, 1) CTILE_F(p, 2) CTILE_F(p, 3)
                    SWRITEP(p + 1, 1)
                    SYNC
                }
                {
                    SLOADP(p + 3, 1)
                    CTILE_F(p + 1, 0) CTILE_F(p + 1, 1) CTILE_F(p + 1, 2) CTILE_F(p + 1, 3)
                    SWRITEP(p + 2, 0)
                    SYNC
                }
            }
        } else {
            for (int p = 0; p < PH; p += 2) {
                {
                    SLOADP(p + 2, 0)
                    CTILE_G(p, 0) CTILE_G(p, 1) CTILE_G(p, 2) CTILE_G(p, 3)
                    SWRITEP(p + 1, 1)
                    SYNC
                }
                if (p + 1 < PH) {
                    SLOADP(p + 3, 1)
                    CTILE_G(p + 1, 0) CTILE_G(p + 1, 1) CTILE_G(p + 1, 2) CTILE_G(p + 1, 3)
                    SWRITEP(p + 2, 0)
                    SYNC
                }
            }
        }
    }
    #undef SLOADP
    #undef SWRITEP
    #undef CTILE_F
    #undef CTILE_G
    #undef SYNC

    // Per-lane valid-row count (analytic).
    float nsum = 0.0f;
    if (K > 0) {
        int nfull = (b < Tf) ? ((Tf - 1 - b) / NB + 1) : 0;
        nsum = 4.0f * (float)nfull;
        if (Tf < T && b <= Tf && ((Tf - b) % NB) == 0) {   // block owns partial tile
            int prem = P - Tf * 16;
            int nv = prem - kg * 4; if (nv < 0) nv = 0; if (nv > 4) nv = 4;
            nsum += (float)nv;
        }
    }

    // sum(tanh) = nsum - 2*sum(sigma); fold 4 row-regs, then 4 k-groups.
    float sA = nsum - 2.0f * ((accA[0] + accA[1]) + (accA[2] + accA[3]));
    sA += __shfl_xor(sA, 16, 64);
    sA += __shfl_xor(sA, 32, 64);
    float sB = nsum - 2.0f * ((accB[0] + accB[1]) + (accB[2] + accB[3]));
    sB += __shfl_xor(sB, 16, 64);
    sB += __shfl_xor(sB, 32, 64);
    if (lane < 16) {
        wacc[g0 * 16 + lane] = sA;
        wacc[g1 * 16 + lane] = sB;
    }
    __syncthreads();
    if (tid < 128) {
        partials[(size_t)b * 128 + tid] = wacc[tid];
    }
}

// Finalize: generic 16-deep-ILP partials reduction (256B/lane in flight;
// the cross-XCD read is latency-bound). cnt = nblk/32 = 64 at nblk=2048.
__global__ __launch_bounds__(1024) void phot_finalize(
    const float* __restrict__ partials, int nblk, int P,
    const float* __restrict__ out_w,      // [32][128]
    const float* __restrict__ out_b,      // [32]
    const float* __restrict__ rel_bias,   // [129][2]
    const float* __restrict__ cand,       // [32]
    const float* __restrict__ norm_scale, // [1]
    const int* __restrict__ posp,         // [1]
    float* __restrict__ out)              // [32]
{
    __shared__ __align__(16) float sh[4096];   // [slice 0..31][128 ch]
    __shared__ float  cm[128];
    __shared__ float  outv[32];
    __shared__ double db[512];
    __shared__ float  bm[2];

    const int t   = threadIdx.x;
    const int chg = t & 31;         // channel group (4 channels)
    const int sl  = t >> 5;         // 0..31 slices over blocks

    const int cnt = nblk >> 5;      // nblk is a multiple of 32
    const float* p0 = partials + (size_t)(sl * cnt) * 128 + chg * 4;
    f32x4 s0 = {0,0,0,0}, s1 = {0,0,0,0}, s2 = {0,0,0,0}, s3 = {0,0,0,0};
    int i = 0;
    for (; i + 16 <= cnt; i += 16) {
        f32x4 v[16];
        #pragma unroll
        for (int j = 0; j < 16; ++j)
            v[j] = *(const f32x4*)(p0 + (size_t)(i + j) * 128);
        #pragma unroll
        for (int j = 0; j < 16; j += 4) {
            s0 += v[j+0]; s1 += v[j+1]; s2 += v[j+2]; s3 += v[j+3];
        }
    }
    for (; i < cnt; ++i) s0 += *(const f32x4*)(p0 + (size_t)i * 128);
    f32x4 acc = (s0 + s1) + (s2 + s3);
    *(f32x4*)&sh[sl * 128 + chg * 4] = acc;
    __syncthreads();

    if (t < 128) {
        float s = 0.0f;
        #pragma unroll
        for (int s2i = 0; s2i < 32; ++s2i) s += sh[t + 128 * s2i];
        cm[t] = s / (float)P;
    }

    // rel-bias mean, closed form per bin; idx(p)=clamp(a+p,0,128), a=pos-P+64
    if (t < 512) {
        const int c = t >> 8, j = t & 255;
        double v = 0.0;
        if (j <= 128) {
            const long long pos = (long long)(*posp);
            const long long a = pos - (long long)P + 64;
            double cnt2;
            if (j == 0) {
                long long hi = -a; if (hi > (long long)P - 1) hi = (long long)P - 1;
                cnt2 = (hi >= 0) ? (double)(hi + 1) : 0.0;
            } else if (j == 128) {
                long long lo = 128 - a; if (lo < 0) lo = 0;
                cnt2 = (lo <= (long long)P - 1) ? (double)((long long)P - lo) : 0.0;
            } else {
                long long p = (long long)j - a;
                cnt2 = (p >= 0 && p < (long long)P) ? 1.0 : 0.0;
            }
            v = cnt2 * (double)rel_bias[2*j + c];
        }
        db[t] = v;
    }
    __syncthreads();
    #pragma unroll
    for (int s = 128; s >= 1; s >>= 1) {
        if (t < 512 && (t & 255) < s) db[t] += db[t + s];
        __syncthreads();
    }
    if (t < 2) bm[t] = (float)(db[t << 8] / (double)P);
    __syncthreads();

    if (t < 32) {
        const float* wr = out_w + t * 128;
        float o0 = out_b[t], o1 = 0.f, o2 = 0.f, o3 = 0.f;
        #pragma unroll
        for (int j = 0; j < 128; j += 4) {
            o0 = fmaf(wr[j+0], cm[j+0], o0);
            o1 = fmaf(wr[j+1], cm[j+1], o1);
            o2 = fmaf(wr[j+2], cm[j+2], o2);
            o3 = fmaf(wr[j+3], cm[j+3], o3);
        }
        outv[t] = (o0+o1) + (o2+o3);
    }
    __syncthreads();

    if (t < 32) {
        float zt = tanh_fast(cand[t] + COUPLING * (outv[t] + bm[t & 1]));
        float other = __shfl_xor(zt, 1, 64);
        float m = fmaf(zt, zt, other * other);
        #pragma unroll
        for (int off = 2; off < 32; off <<= 1) m = fmaxf(m, __shfl_xor(m, off, 64));
        float scale = norm_scale[0] / sqrtf(m + EPSV);
        out[t] = (m > 0.0f) ? zt * scale : zt;
    }
}

extern "C" void kernel_launch(void* const* d_in, const int* in_sizes, int n_in,
                              void* d_out, int out_size, void* d_ws, size_t ws_size,
                              hipStream_t stream)
{
    const float* cand       = (const float*)d_in[0];
    const float* z_past     = (const float*)d_in[1];
    const float* heads_w    = (const float*)d_in[2];
    const float* heads_b    = (const float*)d_in[3];
    const float* out_w      = (const float*)d_in[4];
    const float* out_b      = (const float*)d_in[5];
    const float* rel_bias   = (const float*)d_in[6];
    const float* norm_scale = (const float*)d_in[7];
    const int*   posp       = (const int*)d_in[8];

    const int P = in_sizes[1] / 32;

    int nblk = 2048;     // 8 blocks/CU: LDS 17.3KB x 8 = 139KB <= 160KB,
                         // VGPR ~44 (measured R9 body), T%2048==0 -> uniform
    size_t need = (size_t)nblk * 128 * sizeof(float);
    if (need > ws_size) {
        nblk = (int)(ws_size / (128 * sizeof(float)));
        nblk &= ~31;
        if (nblk < 32) nblk = 32;
    }
    float* partials = (float*)d_ws;

    phot_main<<<nblk, 256, 0, stream>>>(z_past, heads_w, heads_b, cand,
                                        partials, P, nblk);
    phot_finalize<<<1, 1024, 0, stream>>>(partials, nblk, P, out_w, out_b,
                                          rel_bias, cand, norm_scale, posp,
                                          (float*)d_out);
}

// Round 17
// 35.518 us; speedup vs baseline: 1.7513x; 1.2236x over previous
//
#include <hip/hip_runtime.h>
#include <hip/hip_bf16.h>
#include <math.h>

#define COUPLING 0.12f
#define EPSV 1e-8f
#define SCALE2L2E 2.8853900817779268f   // 2*log2(e): folds tanh's 2x and exp->exp2

typedef __attribute__((ext_vector_type(8))) short bf16x8;
typedef __attribute__((ext_vector_type(4))) float f32x4;

// tanh(x) from y = 2x*log2(e):  tanh = 1 - 2/(1+2^y). Inf-safe both ways.
__device__ __forceinline__ float tanh_from_e2(float y) {
    float e = __builtin_amdgcn_exp2f(y);
    float r = __builtin_amdgcn_rcpf(1.0f + e);
    return fmaf(-2.0f, r, 1.0f);
}
__device__ __forceinline__ float tanh_fast(float x) {
    return tanh_from_e2(SCALE2L2E * x);
}
// sigma(y) = 1/(1+2^y); tanh = 1 - 2*sigma.
__device__ __forceinline__ float sig_e2(float y) {
    float e = __builtin_amdgcn_exp2f(y);
    return __builtin_amdgcn_rcpf(1.0f + e);
}

__device__ __forceinline__ short f2bf(float f) {
    __hip_bfloat16 h = __float2bfloat16(f);
    return __builtin_bit_cast(short, h);
}

// Main, round-20: VERBATIM REVERT to the R11-benched best (35.78us).
// Config ledger (16 rounds):
//  - nblk=1024 / 4 blocks/CU / K=32: optimum. 8-blocks/CU failed SIX times
//    (R1 spill, R8 granule straggler, R10 straggler, R12 reg-clamp spill,
//    R13-15 no-LDS line, R16 clean ring-2: K halves -> prologue doubles,
//    co-resident barrier-blocks collide at phase tops).
//  - ring-3 + write-at-phase-bottom + raw s_barrier/lgkmcnt(0): proven.
//  - 2-way swizzle slot = chunk ^ ((row>>1)&3) (R9's 1.8M-conflict counter
//    -> ~0): proven.
//  - uniform fast path (T%NB==0, no partial tile): proven (+0.6us).
// Structural constraint at this plateau: VALU floor ~11.6us (134M quarter-
// rate trans ops, algorithmic), memory floor ~10.6us cold, main ~29-31us;
// the residual is sync/latency-bound and resisted 11 structural attempts
// (source-level pipelining x4, barrier variants x3, occupancy x6, no-LDS
// x3) -- consistent with the documented barrier-drain ceiling of
// compiler-scheduled phase loops on gfx950.
// C/D layout: col=lane&15, row=(lane>>4)*4+reg (m89-verified).
__global__ __launch_bounds__(256, 4) void phot_main(
    const float* __restrict__ z_past,   // [P][32] fp32
    const float* __restrict__ heads_w,  // [128][64]
    const float* __restrict__ heads_b,  // [128]
    const float* __restrict__ cand,     // [32]
    float* __restrict__ partials,       // [NB][128]
    int P, int NB)                      // NB = grid size
{
    __shared__ float wacc[128];
    __shared__ float cpre_l[128];
    __shared__ __align__(16) unsigned short wbf_l[128][32];   // 8KB bf16 weights
    __shared__ __align__(16) unsigned short zb[3][4][512];    // ring: [slot][tile][16x32]

    const int tid  = threadIdx.x;
    const int lane = tid & 63;
    const int wv   = tid >> 6;
    const int col  = lane & 15;   // A-row / B-col / C-col
    const int kg   = lane >> 4;   // k-group (k = kg*8 + e)

    // ---- prep phase (block-local) ----
    if (tid < 128) {
        const float* wr = heads_w + (size_t)tid * 64;
        float s0 = heads_b[tid], s1 = 0.f, s2 = 0.f, s3 = 0.f;
        #pragma unroll
        for (int k = 0; k < 32; k += 4) {
            s0 = fmaf(wr[k+0], cand[k+0], s0);
            s1 = fmaf(wr[k+1], cand[k+1], s1);
            s2 = fmaf(wr[k+2], cand[k+2], s2);
            s3 = fmaf(wr[k+3], cand[k+3], s3);
        }
        cpre_l[tid] = SCALE2L2E * ((s0 + s1) + (s2 + s3));
        #pragma unroll
        for (int k = 0; k < 32; ++k)
            wbf_l[tid][k] = (unsigned short)f2bf(SCALE2L2E * wr[32 + k]);
    }
    __syncthreads();

    // This wave's 2 channel groups (B fragments from LDS).
    const int g0 = wv * 2, g1 = g0 + 1;
    const bf16x8 bfA = *(const bf16x8*)&wbf_l[g0 * 16 + col][kg * 8];
    const bf16x8 bfB = *(const bf16x8*)&wbf_l[g1 * 16 + col][kg * 8];
    const float  cpA = cpre_l[g0 * 16 + col];
    const float  cpB = cpre_l[g1 * 16 + col];
    const f32x4  cvA = {cpA, cpA, cpA, cpA};   // hoisted MFMA C operands
    const f32x4  cvB = {cpB, cpB, cpB, cpB};

    f32x4 accA = {0,0,0,0}, accB = {0,0,0,0};

    const int T  = (P + 15) >> 4;             // total 16-row tiles
    const int Tf = P >> 4;                    // full tiles
    const int b  = blockIdx.x;
    const int K  = (b < T) ? ((T - 1 - b) / NB + 1) : 0;   // tiles for this block
    const int PH = (K + 3) >> 2;              // phases of 4 tiles

    // Uniform shape: every block has the same K, no partial tile, PH even.
    const bool uni = ((T % NB) == 0) && (Tf == T) && ((K & 7) == 0);

    // Stager lane mapping: lane covers tile floats [sr*32 + sc*8, +8).
    const int sr = lane >> 2;                 // row 0..15
    const int sc = lane & 3;                  // chunk 0..3 (8 floats = 16B bf16)
    // Verified 2-way swizzle: slot = chunk ^ ((row>>1)&3).
    const int woff = sr * 32 + ((sc ^ ((sr >> 1) & 3)) << 3);   // ushort offset
    const int roff = col * 32 + ((kg ^ ((col >> 1) & 3)) << 3); // ushort offset

    // Two named prefetch register sets; phase q's data lives in set (q&1).
    f32x4 preA0, preB0, preA1, preB1;

    #define SLOADP(ph, S) { \
        const int j_ = 4 * (ph) + wv; \
        if (j_ < K) { \
            const int tt_ = b + j_ * NB; \
            int grow = tt_ * 16 + sr; if (grow > P - 1) grow = P - 1; \
            const float* g_ = z_past + (size_t)grow * 32 + sc * 8; \
            preA##S = *(const f32x4*)g_; \
            preB##S = *(const f32x4*)(g_ + 4); \
        } }
    #define SWRITEP(ph, S) { \
        const int j_ = 4 * (ph) + wv; \
        if (j_ < K) { \
            bf16x8 w_; \
            w_[0]=f2bf(preA##S[0]); w_[1]=f2bf(preA##S[1]); \
            w_[2]=f2bf(preA##S[2]); w_[3]=f2bf(preA##S[3]); \
            w_[4]=f2bf(preB##S[0]); w_[5]=f2bf(preB##S[1]); \
            w_[6]=f2bf(preB##S[2]); w_[7]=f2bf(preB##S[3]); \
            *(bf16x8*)(&zb[(ph) % 3][wv][woff]) = w_; \
        } }
    // Fast-path tile: no guards, no tail (uniform shape only).
    #define CTILE_F(p, j) { \
        const bf16x8 a_ = *(const bf16x8*)(&zb[(p) % 3][j][roff]); \
        f32x4 d_ = __builtin_amdgcn_mfma_f32_16x16x32_bf16(a_, bfA, cvA, 0, 0, 0); \
        accA[0] += sig_e2(d_[0]); accA[1] += sig_e2(d_[1]); \
        accA[2] += sig_e2(d_[2]); accA[3] += sig_e2(d_[3]); \
        d_ = __builtin_amdgcn_mfma_f32_16x16x32_bf16(a_, bfB, cvB, 0, 0, 0); \
        accB[0] += sig_e2(d_[0]); accB[1] += sig_e2(d_[1]); \
        accB[2] += sig_e2(d_[2]); accB[3] += sig_e2(d_[3]); }
    // Guarded tile (general shapes).
    #define CTILE_G(p, j) { \
        const int jj_ = 4 * (p) + (j); \
        if (jj_ < K) { \
            const int tt_ = b + jj_ * NB; \
            const bf16x8 a_ = *(const bf16x8*)(&zb[(p) % 3][j][roff]); \
            const int base_ = tt_ * 16; \
            if (base_ + 16 <= P) { \
                f32x4 d_ = __builtin_amdgcn_mfma_f32_16x16x32_bf16(a_, bfA, cvA, 0, 0, 0); \
                accA[0] += sig_e2(d_[0]); accA[1] += sig_e2(d_[1]); \
                accA[2] += sig_e2(d_[2]); accA[3] += sig_e2(d_[3]); \
                d_ = __builtin_amdgcn_mfma_f32_16x16x32_bf16(a_, bfB, cvB, 0, 0, 0); \
                accB[0] += sig_e2(d_[0]); accB[1] += sig_e2(d_[1]); \
                accB[2] += sig_e2(d_[2]); accB[3] += sig_e2(d_[3]); \
            } else { \
                const int r0_ = base_ + kg * 4; \
                f32x4 d_ = __builtin_amdgcn_mfma_f32_16x16x32_bf16(a_, bfA, cvA, 0, 0, 0); \
                if (r0_ + 0 < P) accA[0] += sig_e2(d_[0]); \
                if (r0_ + 1 < P) accA[1] += sig_e2(d_[1]); \
                if (r0_ + 2 < P) accA[2] += sig_e2(d_[2]); \
                if (r0_ + 3 < P) accA[3] += sig_e2(d_[3]); \
                d_ = __builtin_amdgcn_mfma_f32_16x16x32_bf16(a_, bfB, cvB, 0, 0, 0); \
                if (r0_ + 0 < P) accB[0] += sig_e2(d_[0]); \
                if (r0_ + 1 < P) accB[1] += sig_e2(d_[1]); \
                if (r0_ + 2 < P) accB[2] += sig_e2(d_[2]); \
                if (r0_ + 3 < P) accB[3] += sig_e2(d_[3]); \
            } \
        } }

    #define SYNC { asm volatile("s_waitcnt lgkmcnt(0)" ::: "memory"); \
                   __builtin_amdgcn_s_barrier(); \
                   __builtin_amdgcn_sched_barrier(0); }

    if (K > 0) {
        // Prologue: phase-0 data -> set 0, publish; phase-1 data -> set 1.
        SLOADP(0, 0)
        SWRITEP(0, 0)             // vmcnt wait (prologue, once)
        SLOADP(1, 1)
        SYNC

        if (uni) {
            // Hot path: loads at phase TOP, publish at BOTTOM, no tile guards.
            for (int p = 0; p < PH; p += 2) {
                {
                    SLOADP(p + 2, 0)
                    CTILE_F(p, 0) CTILE_F(p, 1) CTILE_F(p, 2) CTILE_F(p, 3)
                    SWRITEP(p + 1, 1)
                    SYNC
                }
                {
                    SLOADP(p + 3, 1)
                    CTILE_F(p + 1, 0) CTILE_F(p + 1, 1) CTILE_F(p + 1, 2) CTILE_F(p + 1, 3)
                    SWRITEP(p + 2, 0)
                    SYNC
                }
            }
        } else {
            for (int p = 0; p < PH; p += 2) {
                {
                    SLOADP(p + 2, 0)
                    CTILE_G(p, 0) CTILE_G(p, 1) CTILE_G(p, 2) CTILE_G(p, 3)
                    SWRITEP(p + 1, 1)
                    SYNC
                }
                if (p + 1 < PH) {
                    SLOADP(p + 3, 1)
                    CTILE_G(p + 1, 0) CTILE_G(p + 1, 1) CTILE_G(p + 1, 2) CTILE_G(p + 1, 3)
                    SWRITEP(p + 2, 0)
                    SYNC
                }
            }
        }
    }
    #undef SLOADP
    #undef SWRITEP
    #undef CTILE_F
    #undef CTILE_G
    #undef SYNC

    // Per-lane valid-row count (analytic).
    float nsum = 0.0f;
    if (K > 0) {
        int nfull = (b < Tf) ? ((Tf - 1 - b) / NB + 1) : 0;
        nsum = 4.0f * (float)nfull;
        if (Tf < T && b <= Tf && ((Tf - b) % NB) == 0) {   // block owns partial tile
            int prem = P - Tf * 16;
            int nv = prem - kg * 4; if (nv < 0) nv = 0; if (nv > 4) nv = 4;
            nsum += (float)nv;
        }
    }

    // sum(tanh) = nsum - 2*sum(sigma); fold 4 row-regs, then 4 k-groups.
    float sA = nsum - 2.0f * ((accA[0] + accA[1]) + (accA[2] + accA[3]));
    sA += __shfl_xor(sA, 16, 64);
    sA += __shfl_xor(sA, 32, 64);
    float sB = nsum - 2.0f * ((accB[0] + accB[1]) + (accB[2] + accB[3]));
    sB += __shfl_xor(sB, 16, 64);
    sB += __shfl_xor(sB, 32, 64);
    if (lane < 16) {
        wacc[g0 * 16 + lane] = sA;
        wacc[g1 * 16 + lane] = sB;
    }
    __syncthreads();
    if (tid < 128) {
        partials[(size_t)b * 128 + tid] = wacc[tid];
    }
}

// Finalize: generic 16-deep-ILP partials reduction (256B/lane in flight;
// the cross-XCD read is latency-bound). cnt = nblk/32 = 32 at nblk=1024.
__global__ __launch_bounds__(1024) void phot_finalize(
    const float* __restrict__ partials, int nblk, int P,
    const float* __restrict__ out_w,      // [32][128]
    const float* __restrict__ out_b,      // [32]
    const float* __restrict__ rel_bias,   // [129][2]
    const float* __restrict__ cand,       // [32]
    const float* __restrict__ norm_scale, // [1]
    const int* __restrict__ posp,         // [1]
    float* __restrict__ out)              // [32]
{
    __shared__ __align__(16) float sh[4096];   // [slice 0..31][128 ch]
    __shared__ float  cm[128];
    __shared__ float  outv[32];
    __shared__ double db[512];
    __shared__ float  bm[2];

    const int t   = threadIdx.x;
    const int chg = t & 31;         // channel group (4 channels)
    const int sl  = t >> 5;         // 0..31 slices over blocks

    const int cnt = nblk >> 5;      // nblk is a multiple of 32
    const float* p0 = partials + (size_t)(sl * cnt) * 128 + chg * 4;
    f32x4 s0 = {0,0,0,0}, s1 = {0,0,0,0}, s2 = {0,0,0,0}, s3 = {0,0,0,0};
    int i = 0;
    for (; i + 16 <= cnt; i += 16) {
        f32x4 v[16];
        #pragma unroll
        for (int j = 0; j < 16; ++j)
            v[j] = *(const f32x4*)(p0 + (size_t)(i + j) * 128);
        #pragma unroll
        for (int j = 0; j < 16; j += 4) {
            s0 += v[j+0]; s1 += v[j+1]; s2 += v[j+2]; s3 += v[j+3];
        }
    }
    for (; i < cnt; ++i) s0 += *(const f32x4*)(p0 + (size_t)i * 128);
    f32x4 acc = (s0 + s1) + (s2 + s3);
    *(f32x4*)&sh[sl * 128 + chg * 4] = acc;
    __syncthreads();

    if (t < 128) {
        float s = 0.0f;
        #pragma unroll
        for (int s2i = 0; s2i < 32; ++s2i) s += sh[t + 128 * s2i];
        cm[t] = s / (float)P;
    }

    // rel-bias mean, closed form per bin; idx(p)=clamp(a+p,0,128), a=pos-P+64
    if (t < 512) {
        const int c = t >> 8, j = t & 255;
        double v = 0.0;
        if (j <= 128) {
            const long long pos = (long long)(*posp);
            const long long a = pos - (long long)P + 64;
            double cnt2;
            if (j == 0) {
                long long hi = -a; if (hi > (long long)P - 1) hi = (long long)P - 1;
                cnt2 = (hi >= 0) ? (double)(hi + 1) : 0.0;
            } else if (j == 128) {
                long long lo = 128 - a; if (lo < 0) lo = 0;
                cnt2 = (lo <= (long long)P - 1) ? (double)((long long)P - lo) : 0.0;
            } else {
                long long p = (long long)j - a;
                cnt2 = (p >= 0 && p < (long long)P) ? 1.0 : 0.0;
            }
            v = cnt2 * (double)rel_bias[2*j + c];
        }
        db[t] = v;
    }
    __syncthreads();
    #pragma unroll
    for (int s = 128; s >= 1; s >>= 1) {
        if (t < 512 && (t & 255) < s) db[t] += db[t + s];
        __syncthreads();
    }
    if (t < 2) bm[t] = (float)(db[t << 8] / (double)P);
    __syncthreads();

    if (t < 32) {
        const float* wr = out_w + t * 128;
        float o0 = out_b[t], o1 = 0.f, o2 = 0.f, o3 = 0.f;
        #pragma unroll
        for (int j = 0; j < 128; j += 4) {
            o0 = fmaf(wr[j+0], cm[j+0], o0);
            o1 = fmaf(wr[j+1], cm[j+1], o1);
            o2 = fmaf(wr[j+2], cm[j+2], o2);
            o3 = fmaf(wr[j+3], cm[j+3], o3);
        }
        outv[t] = (o0+o1) + (o2+o3);
    }
    __syncthreads();

    if (t < 32) {
        float zt = tanh_fast(cand[t] + COUPLING * (outv[t] + bm[t & 1]));
        float other = __shfl_xor(zt, 1, 64);
        float m = fmaf(zt, zt, other * other);
        #pragma unroll
        for (int off = 2; off < 32; off <<= 1) m = fmaxf(m, __shfl_xor(m, off, 64));
        float scale = norm_scale[0] / sqrtf(m + EPSV);
        out[t] = (m > 0.0f) ? zt * scale : zt;
    }
}

extern "C" void kernel_launch(void* const* d_in, const int* in_sizes, int n_in,
                              void* d_out, int out_size, void* d_ws, size_t ws_size,
                              hipStream_t stream)
{
    const float* cand       = (const float*)d_in[0];
    const float* z_past     = (const float*)d_in[1];
    const float* heads_w    = (const float*)d_in[2];
    const float* heads_b    = (const float*)d_in[3];
    const float* out_w      = (const float*)d_in[4];
    const float* out_b      = (const float*)d_in[5];
    const float* rel_bias   = (const float*)d_in[6];
    const float* norm_scale = (const float*)d_in[7];
    const int*   posp       = (const int*)d_in[8];

    const int P = in_sizes[1] / 32;

    int nblk = 1024;     // 4 blocks/CU / K=32: six-experiment-verified optimum
    size_t need = (size_t)nblk * 128 * sizeof(float);
    if (need > ws_size) {
        nblk = (int)(ws_size / (128 * sizeof(float)));
        nblk &= ~31;
        if (nblk < 32) nblk = 32;
    }
    float* partials = (float*)d_ws;

    phot_main<<<nblk, 256, 0, stream>>>(z_past, heads_w, heads_b, cand,
                                        partials, P, nblk);
    phot_finalize<<<1, 1024, 0, stream>>>(partials, nblk, P, out_w, out_b,
                                          rel_bias, cand, norm_scale, posp,
                                          (float*)d_out);
}